// Round 8
// baseline (5424.257 us; speedup 1.0000x reference)
//
#include <hip/hip_runtime.h>
#include <math.h>

// RipsLayer: dim-0 persistence of Rips filtration on 4096 points in R^64.
// Phase 1: dense distance matrix D (64 MiB, in d_ws), diagonal = -INF.
// Phase 2: exact Prim replay on a SINGLE WAVE (64 lanes):
//   - zero barriers / LDS / atomics -- all cross-lane via DPP + readlane
//   - lane L owns cols {256q + 4L + l : q=0..15, l=0..3} (interleaved ->
//     every row-load instruction is a perfectly coalesced contiguous 1KB)
//   - diag=-INF sticky fold + free |.| modifiers mask tree cols
//   - exact ties: local tournament strict-< keeps lowest local col;
//     cross-lane lowest col via u32 DPP min over tied lanes

#define N 4096
#define DF 64
#define INF __builtin_huge_valf()

// ---------------------------------------------------------------------------
// Phase 1: D[i][j] = sqrt(max(|x_i - x_j|^2, 1e-12)), diag = -INF (internal).
// ---------------------------------------------------------------------------
__global__ __launch_bounds__(256) void build_d_kernel(const float* __restrict__ x,
                                                      float* __restrict__ D) {
    __shared__ float As[64][68];
    __shared__ float Bs[64][68];
    const int bi = blockIdx.y * 64;
    const int bj = blockIdx.x * 64;
    const int t = threadIdx.x;

#pragma unroll
    for (int g = 0; g < 4; ++g) {
        int idx = t + 256 * g;
        int row = idx >> 4;
        int k4 = (idx & 15) << 2;
        float4 va = *(const float4*)(x + (size_t)(bi + row) * DF + k4);
        float4 vb = *(const float4*)(x + (size_t)(bj + row) * DF + k4);
        *(float4*)(&As[row][k4]) = va;
        *(float4*)(&Bs[row][k4]) = vb;
    }
    __syncthreads();

    const int ti = (t >> 4) << 2;
    const int tj = (t & 15) << 2;

    float acc[4][4];
#pragma unroll
    for (int r = 0; r < 4; ++r)
#pragma unroll
        for (int c = 0; c < 4; ++c) acc[r][c] = 0.0f;

    for (int k = 0; k < 64; k += 4) {
        float4 a[4], b[4];
#pragma unroll
        for (int r = 0; r < 4; ++r) a[r] = *(const float4*)(&As[ti + r][k]);
#pragma unroll
        for (int c = 0; c < 4; ++c) b[c] = *(const float4*)(&Bs[tj + c][k]);
#pragma unroll
        for (int r = 0; r < 4; ++r)
#pragma unroll
            for (int c = 0; c < 4; ++c) {
                float d0 = a[r].x - b[c].x;
                float d1 = a[r].y - b[c].y;
                float d2 = a[r].z - b[c].z;
                float d3 = a[r].w - b[c].w;
                float s = acc[r][c];
                s = fmaf(d0, d0, s);
                s = fmaf(d1, d1, s);
                s = fmaf(d2, d2, s);
                s = fmaf(d3, d3, s);
                acc[r][c] = s;
            }
    }

#pragma unroll
    for (int r = 0; r < 4; ++r) {
        int i = bi + ti + r;
        float4 v;
        float* vp = &v.x;
#pragma unroll
        for (int c = 0; c < 4; ++c) {
            int j = bj + tj + c;
            vp[c] = (i == j) ? -INF : sqrtf(fmaxf(acc[r][c], 1e-12f));
        }
        *(float4*)(D + (size_t)i * N + (bj + tj)) = v;
    }
}

// ---------------------------------------------------------------------------
// Wave64 DPP reductions (result lands in lane 63). Pattern verified exact
// in rounds 5-7 (absmax 0.0).
// ---------------------------------------------------------------------------
#define DPP_FMIN_STEP(x, ctrl)                                                 \
    x = fminf(x, __int_as_float(__builtin_amdgcn_update_dpp(                   \
                     0x7f800000, __float_as_int(x), ctrl, 0xF, 0xF, false)))

#define DPP_UMIN_STEP(x, ctrl)                                                 \
    {                                                                          \
        unsigned _o = (unsigned)__builtin_amdgcn_update_dpp(                   \
            0x7fffffff, (int)(x), ctrl, 0xF, 0xF, false);                      \
        x = (_o < (x)) ? _o : (x);                                             \
    }

// ---------------------------------------------------------------------------
// Phase 2: single wave. mv element idx=(4q+l) of lane L <-> col 256q+4L+l.
// Invariant: mv == -INF exactly at in-tree cols (diag trick auto-pins).
// ---------------------------------------------------------------------------
__global__ __launch_bounds__(64) void prim_kernel(const float* __restrict__ D,
                                                  float* __restrict__ out) {
    const int L = threadIdx.x;  // lane 0..63

    float4 mv[16];  // mind (chunk q = cols [256q+4L, 256q+4L+4))
    float4 rv[16];  // row of last-selected vertex
    {
        const float4* r0 = (const float4*)D;  // row 0; D[0][0] = -INF
#pragma unroll
        for (int q = 0; q < 16; ++q) {
            float4 a = r0[64 * q + L];
            mv[q] = a;
            rv[q] = a;  // fold of row0 into row0 is a no-op (min(a,a)=a)
        }
    }

#pragma unroll 1
    for (int s = 1; s < N; ++s) {
        // ---- fold: mind = min(mind, row_j); -INF tree cols stay -INF,
        //      and row_j's own -INF diagonal auto-pins col j ----
#pragma unroll
        for (int q = 0; q < 16; ++q) {
            mv[q].x = fminf(mv[q].x, rv[q].x);
            mv[q].y = fminf(mv[q].y, rv[q].y);
            mv[q].z = fminf(mv[q].z, rv[q].z);
            mv[q].w = fminf(mv[q].w, rv[q].w);
        }

        // ---- local id-carrying tournament over |mv| (64 -> 1) ----
        // strict '<' keeps the lowest element index on ties; element index
        // ascending == owned-column ascending, so local ties are exact.
        float v[32];
        int id[32];
#pragma unroll
        for (int p = 0; p < 32; ++p) {
            float a = ((const float*)&mv[(2 * p) >> 2])[(2 * p) & 3];
            float b = ((const float*)&mv[(2 * p + 1) >> 2])[(2 * p + 1) & 3];
            bool c = fabsf(b) < fabsf(a);  // abs folds into VOP modifiers
            v[p] = fminf(fabsf(a), fabsf(b));
            id[p] = 2 * p + (c ? 1 : 0);
        }
#pragma unroll
        for (int st = 1; st < 32; st <<= 1)
#pragma unroll
            for (int i = 0; i < 32; i += 2 * st)
                if (v[i + st] < v[i]) {  // strict: keep lower idx on ties
                    v[i] = v[i + st];
                    id[i] = id[i + st];
                }
        float lv = v[0];
        int lcol = 4 * L + ((id[0] >> 2) << 8) + (id[0] & 3);

        // ---- wave min value (f32 DPP chain, result in lane 63) ----
        float x = lv;
        DPP_FMIN_STEP(x, 0x111);  // row_shr:1
        DPP_FMIN_STEP(x, 0x112);  // row_shr:2
        DPP_FMIN_STEP(x, 0x114);  // row_shr:4
        DPP_FMIN_STEP(x, 0x118);  // row_shr:8
        DPP_FMIN_STEP(x, 0x142);  // row_bcast:15
        DPP_FMIN_STEP(x, 0x143);  // row_bcast:31
        int wmbits = __builtin_amdgcn_readlane(__float_as_int(x), 63);
        float wm = __int_as_float(wmbits);

        // ---- exact lowest column among tied lanes (u32 DPP min) ----
        unsigned cand = (lv == wm) ? (unsigned)lcol : 0x7fffffffu;
        DPP_UMIN_STEP(cand, 0x111);
        DPP_UMIN_STEP(cand, 0x112);
        DPP_UMIN_STEP(cand, 0x114);
        DPP_UMIN_STEP(cand, 0x118);
        DPP_UMIN_STEP(cand, 0x142);
        DPP_UMIN_STEP(cand, 0x143);
        int j = __builtin_amdgcn_readlane((int)cand, 63);

        // ---- issue next row load (16 coalesced dwordx4), consumed at the
        //      top of the next iteration ----
        const float4* rp = (const float4*)(D + (size_t)(unsigned)j * N);
#pragma unroll
        for (int q = 0; q < 16; ++q) rv[q] = rp[64 * q + L];

        if (L == 0)
            *(float2*)(out + 2 * (s - 1)) = make_float2(0.0f, wm);
    }
}

// ---------------------------------------------------------------------------
extern "C" void kernel_launch(void* const* d_in, const int* in_sizes, int n_in,
                              void* d_out, int out_size, void* d_ws, size_t ws_size,
                              hipStream_t stream) {
    const float* x = (const float*)d_in[0];
    float* D = (float*)d_ws;     // requires ws_size >= N*N*4 = 64 MiB
    float* out = (float*)d_out;  // [N-1][2]: (birth=0, death)

    dim3 grid(N / 64, N / 64);
    build_d_kernel<<<grid, 256, 0, stream>>>(x, D);
    prim_kernel<<<1, 64, 0, stream>>>(D, out);
}

// Round 9
// 5288.102 us; speedup vs baseline: 1.0257x; 1.0257x over previous
//
#include <hip/hip_runtime.h>
#include <math.h>

// RipsLayer: dim-0 persistence of Rips filtration on 4096 points in R^64.
// NEW STRUCTURE (R9): parallel Boruvka MST over the complete graph (distances
// computed on the fly, no 64MB D matrix), then exact Prim-order replay on the
// sparse MST (N-1 edges) on a single wave. Deaths = MST edge weights in Prim
// insertion order == reference output (cut property; distinct f32 weights).

#define N 4096
#define INF __builtin_huge_valf()
#define INFBITS 0x7f800000u
#define NINFBITS 0xff800000u
typedef unsigned long long ull;

// ---------------------------------------------------------------------------
// Workspace layout
// ---------------------------------------------------------------------------
struct WS {
    unsigned comp[N];      // component id (root vertex)
    unsigned par[N];       // hook/pointer-jump scratch
    unsigned tgt[N];       // hook targets (per old root)
    ull      minedge[N];   // per-component min edge key (dbits<<24|j<<12|i)
    ull      ebuf[N];      // collected MST edge keys
    unsigned ecnt;
    unsigned done;
    unsigned pad[2];
    unsigned off[N + 4];   // CSR offsets (2-way adjacency)
    ull      adj[2 * N];   // entries: (wbits<<32)|nbr
};

// ---------------------------------------------------------------------------
// k_init
// ---------------------------------------------------------------------------
__global__ __launch_bounds__(1024) void k_init(WS* W) {
    int v = blockIdx.x * 1024 + threadIdx.x;
    if (v < N) {
        W->comp[v] = (unsigned)v;
        W->minedge[v] = ~0ull;
    }
    if (blockIdx.x == 0 && threadIdx.x == 0) { W->ecnt = 0; W->done = 0; }
}

// ---------------------------------------------------------------------------
// k_minedge: per round, for each vertex row compute min external edge key and
// atomicMin into its component slot. Distances computed on the fly, bitwise
// identical to the previous rounds' D (same fmaf order, sqrt(max(.,1e-12))).
// grid = (8 jparts, 64 row-slabs), 256 threads.
// ---------------------------------------------------------------------------
__global__ __launch_bounds__(256) void k_minedge(const float* __restrict__ x,
                                                 WS* __restrict__ W) {
    if (W->done) return;
    __shared__ float As[64][68];
    __shared__ float Bs[64][68];
    __shared__ ull red[64][17];
    const int t = threadIdx.x;
    const int bi = blockIdx.y * 64;   // rows [bi, bi+64)
    const int jp = blockIdx.x * 512;  // cols [jp, jp+512)

    // stage A rows once
#pragma unroll
    for (int g = 0; g < 4; ++g) {
        int idx = t + 256 * g;
        int row = idx >> 4;
        int k4 = (idx & 15) << 2;
        *(float4*)(&As[row][k4]) =
            *(const float4*)(x + (size_t)(bi + row) * 64 + k4);
    }

    const int ti = (t >> 4) << 2;  // 4 rows
    const int tj = (t & 15) << 2;  // 4 cols in tile
    unsigned ci[4];
#pragma unroll
    for (int r = 0; r < 4; ++r) ci[r] = W->comp[bi + ti + r];

    ull rk[4] = {~0ull, ~0ull, ~0ull, ~0ull};

    for (int tile = 0; tile < 8; ++tile) {
        const int jb = jp + tile * 64;
        __syncthreads();  // protect Bs reuse (also covers As on tile 0)
#pragma unroll
        for (int g = 0; g < 4; ++g) {
            int idx = t + 256 * g;
            int row = idx >> 4;
            int k4 = (idx & 15) << 2;
            *(float4*)(&Bs[row][k4]) =
                *(const float4*)(x + (size_t)(jb + row) * 64 + k4);
        }
        __syncthreads();
        unsigned cj[4];
#pragma unroll
        for (int c = 0; c < 4; ++c) cj[c] = W->comp[jb + tj + c];

        float acc[4][4];
#pragma unroll
        for (int r = 0; r < 4; ++r)
#pragma unroll
            for (int c = 0; c < 4; ++c) acc[r][c] = 0.0f;
        for (int k = 0; k < 64; k += 4) {
            float4 a[4], b[4];
#pragma unroll
            for (int r = 0; r < 4; ++r) a[r] = *(const float4*)(&As[ti + r][k]);
#pragma unroll
            for (int c = 0; c < 4; ++c) b[c] = *(const float4*)(&Bs[tj + c][k]);
#pragma unroll
            for (int r = 0; r < 4; ++r)
#pragma unroll
                for (int c = 0; c < 4; ++c) {
                    float d0 = a[r].x - b[c].x;
                    float d1 = a[r].y - b[c].y;
                    float d2 = a[r].z - b[c].z;
                    float d3 = a[r].w - b[c].w;
                    float s = acc[r][c];
                    s = fmaf(d0, d0, s);
                    s = fmaf(d1, d1, s);
                    s = fmaf(d2, d2, s);
                    s = fmaf(d3, d3, s);
                    acc[r][c] = s;
                }
        }
#pragma unroll
        for (int r = 0; r < 4; ++r)
#pragma unroll
            for (int c = 0; c < 4; ++c) {
                if (ci[r] != cj[c]) {
                    float d = sqrtf(fmaxf(acc[r][c], 1e-12f));
                    ull key = ((ull)__float_as_uint(d) << 24) |
                              ((ull)(unsigned)(jb + tj + c) << 12) |
                              (ull)(unsigned)(bi + ti + r);
                    if (key < rk[r]) rk[r] = key;
                }
            }
    }
    __syncthreads();
#pragma unroll
    for (int r = 0; r < 4; ++r) red[ti + r][t & 15] = rk[r];
    __syncthreads();
    if (t < 64) {
        ull k = red[t][0];
#pragma unroll
        for (int c = 1; c < 16; ++c) {
            ull o = red[t][c];
            if (o < k) k = o;
        }
        if (k != ~0ull) atomicMin(&W->minedge[W->comp[bi + t]], k);
    }
}

// ---------------------------------------------------------------------------
// k_hook: hook components along min edges, break 2-cycles (mutual hooks share
// the same edge -> emit once), pointer-jump to compress, recount, reset.
// Single block, 1024 threads, 4 vertices each.
// ---------------------------------------------------------------------------
__global__ __launch_bounds__(1024) void k_hook(WS* __restrict__ W) {
    if (W->done) return;
    const int t = threadIdx.x;
    __shared__ unsigned cnt[1024];

#pragma unroll
    for (int k = 0; k < 4; ++k) {
        int v = t + 1024 * k;
        W->tgt[v] = 0xffffffffu;
        W->par[v] = W->comp[v];
    }
    __syncthreads();
#pragma unroll
    for (int k = 0; k < 4; ++k) {
        int v = t + 1024 * k;
        if (W->comp[v] == (unsigned)v) {
            ull me = W->minedge[v];
            if (me != ~0ull) {
                unsigned j = (unsigned)(me >> 12) & 0xfffu;
                W->tgt[v] = W->comp[j];
            }
        }
    }
    __syncthreads();
#pragma unroll
    for (int k = 0; k < 4; ++k) {
        int v = t + 1024 * k;
        unsigned u = W->tgt[v];
        if (u != 0xffffffffu) {
            bool mutual = (W->tgt[u] == (unsigned)v);
            if (!(mutual && (unsigned)v < u)) {
                W->par[v] = u;
                unsigned idx = atomicAdd(&W->ecnt, 1u);
                W->ebuf[idx] = W->minedge[v];
            }
        }
    }
    __syncthreads();
    for (int it = 0; it < 12; ++it) {
#pragma unroll
        for (int k = 0; k < 4; ++k) {
            int v = t + 1024 * k;
            W->par[v] = W->par[W->par[v]];
        }
        __syncthreads();
    }
#pragma unroll
    for (int k = 0; k < 4; ++k) {
        int v = t + 1024 * k;
        W->comp[v] = W->par[v];
    }
    __syncthreads();
    unsigned c = 0;
#pragma unroll
    for (int k = 0; k < 4; ++k) {
        int v = t + 1024 * k;
        c += (W->comp[v] == (unsigned)v);
    }
    cnt[t] = c;
    __syncthreads();
    for (int st = 512; st > 0; st >>= 1) {
        if (t < st) cnt[t] += cnt[t + st];
        __syncthreads();
    }
    if (t == 0 && cnt[0] == 1u) W->done = 1u;
#pragma unroll
    for (int k = 0; k < 4; ++k) W->minedge[t + 1024 * k] = ~0ull;
}

// ---------------------------------------------------------------------------
// k_csr: build 2-way adjacency (CSR) from the N-1 collected edges.
// ---------------------------------------------------------------------------
__global__ __launch_bounds__(1024) void k_csr(WS* __restrict__ W) {
    __shared__ unsigned deg[N];
    __shared__ unsigned ps[1024];
    const int t = threadIdx.x;
#pragma unroll
    for (int k = 0; k < 4; ++k) deg[t + 1024 * k] = 0;
    __syncthreads();
#pragma unroll
    for (int k = 0; k < 4; ++k) {
        int e = t + 1024 * k;
        if (e < N - 1) {
            ull key = W->ebuf[e];
            unsigned i = (unsigned)key & 0xfffu;
            unsigned j = (unsigned)(key >> 12) & 0xfffu;
            atomicAdd(&deg[i], 1u);
            atomicAdd(&deg[j], 1u);
        }
    }
    __syncthreads();
    unsigned a0 = deg[4 * t], a1 = deg[4 * t + 1];
    unsigned a2 = deg[4 * t + 2], a3 = deg[4 * t + 3];
    ps[t] = a0 + a1 + a2 + a3;
    __syncthreads();
    for (int d = 1; d < 1024; d <<= 1) {
        unsigned v = (t >= d) ? ps[t - d] : 0u;
        __syncthreads();
        ps[t] += v;
        __syncthreads();
    }
    unsigned base = (t > 0) ? ps[t - 1] : 0u;
    unsigned o0 = base, o1 = o0 + a0, o2 = o1 + a1, o3 = o2 + a2;
    W->off[4 * t] = o0; W->off[4 * t + 1] = o1;
    W->off[4 * t + 2] = o2; W->off[4 * t + 3] = o3;
    deg[4 * t] = o0; deg[4 * t + 1] = o1;
    deg[4 * t + 2] = o2; deg[4 * t + 3] = o3;
    if (t == 1023) W->off[N] = ps[1023];
    __syncthreads();
#pragma unroll
    for (int k = 0; k < 4; ++k) {
        int e = t + 1024 * k;
        if (e < N - 1) {
            ull key = W->ebuf[e];
            unsigned i = (unsigned)key & 0xfffu;
            unsigned j = (unsigned)(key >> 12) & 0xfffu;
            unsigned wb = (unsigned)(key >> 24);
            unsigned p = atomicAdd(&deg[i], 1u);
            W->adj[p] = ((ull)wb << 32) | j;
            unsigned q = atomicAdd(&deg[j], 1u);
            W->adj[q] = ((ull)wb << 32) | i;
        }
    }
}

// ---------------------------------------------------------------------------
// k_replay: exact Prim order on the MST, single wave.
// mind[] in LDS (f32 bits; removed = -INF, sticky under fmin). Lane L owns
// cols [64L,64L+64) = groups [8L,8L+8); per-lane register cache of 8 u64
// keys (mappedbits<<32|col) == exact group argmin (value then lowest col).
// ---------------------------------------------------------------------------
#define DPP_UMIN_STEP(x, ctrl)                                                 \
    {                                                                          \
        unsigned _o = (unsigned)__builtin_amdgcn_update_dpp(                   \
            0x7fffffff, (int)(x), ctrl, 0xF, 0xF, false);                      \
        x = (_o < (x)) ? _o : (x);                                             \
    }

__device__ __forceinline__ void upd_entry(ull cache[8], unsigned* mindb,
                                          ull ent, int L) {
    unsigned nbr = (unsigned)ent;
    unsigned wb = (unsigned)(ent >> 32);
    if ((int)(nbr >> 6) == L) {
        float m = __uint_as_float(mindb[nbr]);
        float m2 = fminf(m, __uint_as_float(wb));
        unsigned m2b = __float_as_uint(m2);
        mindb[nbr] = m2b;
        unsigned mm = (m2b == NINFBITS) ? INFBITS : m2b;
        ull kk = ((ull)mm << 32) | nbr;
        int slot = (int)((nbr >> 3) & 7u);
#pragma unroll
        for (int u = 0; u < 8; ++u)
            if (u == slot) cache[u] = (kk < cache[u]) ? kk : cache[u];
    }
}

__device__ __forceinline__ void process_adj(ull cache[8], unsigned* mindb,
                                            const unsigned* offs,
                                            const ull* __restrict__ adj,
                                            unsigned j, int L) {
    unsigned o0 = offs[j];
    unsigned dg = offs[j + 1] - o0;
    // uniform-address loads (one L2 request each), 4 eager + rare tail
    ull e0 = adj[o0];
    ull e1 = adj[o0 + (1u < dg ? 1u : 0u)];
    ull e2 = adj[o0 + (2u < dg ? 2u : 0u)];
    ull e3 = adj[o0 + (3u < dg ? 3u : 0u)];
    upd_entry(cache, mindb, e0, L);
    if (1u < dg) upd_entry(cache, mindb, e1, L);
    if (2u < dg) upd_entry(cache, mindb, e2, L);
    if (3u < dg) upd_entry(cache, mindb, e3, L);
    for (unsigned k = 4; k < dg; ++k) upd_entry(cache, mindb, adj[o0 + k], L);
}

__global__ __launch_bounds__(64) void k_replay(const WS* __restrict__ W,
                                               float* __restrict__ out) {
    __shared__ unsigned mindb[N];
    __shared__ unsigned offs[N + 1];
    const int L = threadIdx.x;

#pragma unroll
    for (int q = 0; q < 16; ++q) {
        uint4 v = {INFBITS, INFBITS, INFBITS, INFBITS};
        *(uint4*)&mindb[64 * L + 4 * q] = v;
    }
    for (int k = L; k <= N; k += 64) offs[k] = W->off[k];
    ull cache[8];
#pragma unroll
    for (int g = 0; g < 8; ++g) cache[g] = ~0ull;
    __syncthreads();

    // add vertex 0
    if (L == 0) mindb[0] = NINFBITS;
    __asm__ __volatile__("" ::: "memory");
    process_adj(cache, mindb, offs, W->adj, 0u, L);
    __asm__ __volatile__("" ::: "memory");

#pragma unroll 1
    for (int s = 1; s < N; ++s) {
        // local argmin: u64 min over 8 group keys (value, then lowest col)
        ull b0 = cache[0] < cache[1] ? cache[0] : cache[1];
        ull b1 = cache[2] < cache[3] ? cache[2] : cache[3];
        ull b2 = cache[4] < cache[5] ? cache[4] : cache[5];
        ull b3 = cache[6] < cache[7] ? cache[6] : cache[7];
        ull b4 = b0 < b1 ? b0 : b1;
        ull b5 = b2 < b3 ? b2 : b3;
        ull bk = b4 < b5 ? b4 : b5;
        unsigned lv = (unsigned)(bk >> 32);

        unsigned xm = lv;
        DPP_UMIN_STEP(xm, 0x111);
        DPP_UMIN_STEP(xm, 0x112);
        DPP_UMIN_STEP(xm, 0x114);
        DPP_UMIN_STEP(xm, 0x118);
        DPP_UMIN_STEP(xm, 0x142);
        DPP_UMIN_STEP(xm, 0x143);
        unsigned wm = (unsigned)__builtin_amdgcn_readlane((int)xm, 63);
        ull tied = __ballot(lv == wm);
        int src = __ffsll(tied) - 1;  // lowest lane == lowest col (blocked)
        unsigned j = (unsigned)__builtin_amdgcn_readlane((int)(unsigned)bk, src);

        if (L == 0)
            *(float2*)(out + 2 * (s - 1)) =
                make_float2(0.0f, __uint_as_float(wm));

        // removal + exact group-cache rebuild (owner lane)
        unsigned gbase = (j >> 3) << 3;
        uint4 ga = *(const uint4*)&mindb[gbase];
        uint4 gb = *(const uint4*)&mindb[gbase + 4];
        if ((int)(j >> 6) == L) {
            mindb[j] = NINFBITS;
            unsigned vals[8] = {ga.x, ga.y, ga.z, ga.w, gb.x, gb.y, gb.z, gb.w};
            ull nk = ~0ull;
#pragma unroll
            for (int u = 0; u < 8; ++u) {
                unsigned m = vals[u];
                if ((unsigned)u == (j & 7u)) m = INFBITS;
                if (m == NINFBITS) m = INFBITS;
                ull kk = ((ull)m << 32) | (gbase + (unsigned)u);
                if (kk < nk) nk = kk;
            }
            int slot = (int)((j >> 3) & 7u);
#pragma unroll
            for (int u = 0; u < 8; ++u)
                if (u == slot) cache[u] = nk;
        }
        __asm__ __volatile__("" ::: "memory");

        // relax MST neighbors of j (removed cols sticky at -INF)
        process_adj(cache, mindb, offs, W->adj, j, L);
        __asm__ __volatile__("" ::: "memory");
    }
}

// ---------------------------------------------------------------------------
extern "C" void kernel_launch(void* const* d_in, const int* in_sizes, int n_in,
                              void* d_out, int out_size, void* d_ws, size_t ws_size,
                              hipStream_t stream) {
    const float* x = (const float*)d_in[0];
    float* out = (float*)d_out;  // [N-1][2]: (birth=0, death)
    WS* W = (WS*)d_ws;           // ~200 KB scratch

    k_init<<<4, 1024, 0, stream>>>(W);
    for (int r = 0; r < 12; ++r) {
        k_minedge<<<dim3(8, 64), 256, 0, stream>>>(x, W);
        k_hook<<<1, 1024, 0, stream>>>(W);
    }
    k_csr<<<1, 1024, 0, stream>>>(W);
    k_replay<<<1, 64, 0, stream>>>(W, out);
}